// Round 13
// baseline (129.956 us; speedup 1.0000x reference)
//
#include <hip/hip_runtime.h>
#include <hip/hip_fp16.h>

// Batched quantum-circuit sim. ONE launch, 1-D grid, 256-thread blocks,
// two UNIFORM block roles — both bodies byte-identical to R12's verified
// kernel (66us dispatch, WRITE=ideal, VGPR=120):
//  - blocks [0, gx):     ABC role: one thread/element, sims A+B+C,
//                        writes out[b*9+0..5]
//  - blocks [gx, 2*gx):  7q role: one thread/element, S128 SSA state,
//                        writes out[b*9+6..8]
// WHY: R12 was grid-limited — 512 blocks = 2048 waves = 2/SIMD, while
// VGPR=120 (128-bucket) permits 4/SIMD. Splitting roles doubles the wave
// supply (4096 = exactly the residency cap) at unchanged total instruction
// count. Pure scheduling change, zero new math.
// __launch_bounds__(256,2): loose bounds only (R10/R11: tight budgets make
// the allocator spill the state tuple wholesale).

#define DEVINL __device__ __forceinline__

typedef _Float16 hv2 __attribute__((ext_vector_type(2)));
typedef unsigned int u32;
typedef u32 vreg16 __attribute__((ext_vector_type(16)));
typedef u32 vreg64 __attribute__((ext_vector_type(64)));

struct C2 { __half2 rr, mp; };  // complex const (r,i): rr=(r,r), mp=(-i,+i)

DEVINL C2 mkc(float re, float im) {
  C2 c; c.rr = __floats2half2_rn(re, re); c.mp = __floats2half2_rn(-im, im); return c;
}
DEVINL __half2 mkamp(float re, float im) { return __floats2half2_rn(re, im); }
DEVINL __half2 swap2(__half2 v) { return __lowhigh2highlow(v); }
// (const u) * (amp v):  (r*vr - i*vi, r*vi + i*vr)
DEVINL __half2 cmulc(C2 u, __half2 v) { return __hfma2(u.rr, v, __hmul2(u.mp, swap2(v))); }

DEVINL float ampsq(__half2 v, float acc) {
#if __has_builtin(__builtin_amdgcn_fdot2)
  return __builtin_amdgcn_fdot2(__builtin_bit_cast(hv2, v), __builtin_bit_cast(hv2, v), acc, false);
#else
  float2 f = __half22float2(v);
  return fmaf(f.x, f.x, fmaf(f.y, f.y, acc));
#endif
}

constexpr int parc(int x) { x ^= x >> 4; x ^= x >> 2; x ^= x >> 1; return x & 1; }

struct c32 { float x, y; };
DEVINL c32 cmulf(c32 a, c32 b) { return { a.x*b.x - a.y*b.y, a.x*b.y + a.y*b.x }; }

// ---- SSA state accessors ----------------------------------------------------
template<class VT>
DEVINL __half2 vget(const VT& A, int i) { return __builtin_bit_cast(__half2, (u32)A[i]); }
template<class VT>
DEVINL void vset(VT& A, int i, __half2 v) { A[i] = __builtin_bit_cast(u32, v); }

// 128-amp state = two vreg64 tuples; index folds to constant after unroll.
struct S128 { vreg64 lo, hi; };
DEVINL __half2 vget(const S128& A, int i) {
  u32 u = (i < 64) ? (u32)A.lo[i] : (u32)A.hi[i - 64];
  return __builtin_bit_cast(__half2, u);
}
DEVINL void vset(S128& A, int i, __half2 v) {
  u32 u = __builtin_bit_cast(u32, v);
  if (i < 64) A.lo[i] = u; else A.hi[i - 64] = u;
}

// ---------------- generic gates (qubit W of N; mask = 1<<(N-1-W)) -----------

template<int N, int W, class VT>
DEVINL void g_ry(VT& A, __half2 c2, __half2 s2, __half2 ns2) {
  constexpr int M = 1 << (N - 1 - W);
#pragma unroll
  for (int i = 0; i < (1 << N); ++i) if (!(i & M)) {
    const int j = i | M;
    __half2 v0 = vget(A, i), v1 = vget(A, j);
    vset(A, i, __hfma2(c2, v0, __hmul2(ns2, v1)));
    vset(A, j, __hfma2(c2, v1, __hmul2(s2, v0)));
  }
}

template<int N, int W, class VT>
DEVINL void g_u2(VT& A, C2 u00, C2 u01, C2 u10, C2 u11) {
  constexpr int M = 1 << (N - 1 - W);
#pragma unroll
  for (int i = 0; i < (1 << N); ++i) if (!(i & M)) {
    const int j = i | M;
    __half2 v0 = vget(A, i), v1 = vget(A, j), v0s = swap2(v0), v1s = swap2(v1);
    vset(A, i, __hfma2(u00.rr, v0, __hfma2(u00.mp, v0s, __hfma2(u01.rr, v1, __hmul2(u01.mp, v1s)))));
    vset(A, j, __hfma2(u10.rr, v0, __hfma2(u10.mp, v0s, __hfma2(u11.rr, v1, __hmul2(u11.mp, v1s)))));
  }
}

template<int N, int C, int T, class VT>
DEVINL void g_cnot(VT& A) {
  constexpr int CM = 1 << (N - 1 - C), TM = 1 << (N - 1 - T);
#pragma unroll
  for (int i = 0; i < (1 << N); ++i) if ((i & CM) && !(i & TM)) {
    const int j = i | TM;
    __half2 t = vget(A, i); vset(A, i, vget(A, j)); vset(A, j, t);
  }
}

template<int N, int K, class VT>
DEVINL void chain_cnot(VT& A) {
  if constexpr (K < N - 1) { g_cnot<N, K, K + 1>(A); chain_cnot<N, K + 1>(A); }
}

// ---------------- per-qubit coefficients (f32) ------------------------------
// forward: u = Rz(phi)Ry(pt)Rx(eta)|0>;  reverse merged: U = Rx(phi)Ry(pt)Rz(eta)

DEVINL void mk_u01(float ce, float se, float cp, float sp, float cf, float sf,
                   c32& u0, c32& u1) {
  u0 = cmulf({cf, -sf}, {cp * ce, sp * se});
  u1 = cmulf({cf,  sf}, {sp * ce, -cp * se});
}

DEVINL void mk_U(float ce, float se, float cp, float sp, float cf, float sf,
                 C2& U00, C2& U01, C2& U10, C2& U11) {
  c32 z = {ce, -se}, zb = {ce, se};
  c32 A = cmulf({cf * cp, -sf * sp}, z);
  c32 T = cmulf({cf * sp,  sf * cp}, zb);
  c32 Cc = cmulf({cf * sp, -sf * cp}, z);
  c32 D = cmulf({cf * cp,  sf * sp}, zb);
  U00 = mkc(A.x, A.y); U01 = mkc(-T.x, -T.y); U10 = mkc(Cc.x, Cc.y); U11 = mkc(D.x, D.y);
}

// per-qubit sincos loader (eta_i<0 -> eta=0)
DEVINL void load_sc(const float* __restrict__ xr, int eta_i, int pt_i, int phi_i,
                    float& ce, float& se, float& cp, float& sp, float& cf, float& sf) {
  float e = (eta_i < 0) ? 0.f : xr[eta_i];
  __sincosf(0.5f * e, &se, &ce);
  __sincosf(0.5f * xr[pt_i], &sp, &cp);
  __sincosf(0.5f * xr[phi_i], &sf, &cf);
}

// product state build by doubling (A[0] must be (1,0) on entry).
// step M's qubit lands at bit (N-1-M). CF(M,u0,u1) supplies the column.
template<int N, int M, class VT, class CF>
DEVINL void build_rec(VT& A, CF cf) {
  if constexpr (M < N) {
    c32 u0, u1; cf(M, u0, u1);
    C2 c0 = mkc(u0.x, u0.y), c1 = mkc(u1.x, u1.y);
#pragma unroll
    for (int j = (1 << M) - 1; j >= 0; --j) {
      __half2 s = vget(A, j);
      vset(A, 2 * j,     cmulc(c0, s));
      vset(A, 2 * j + 1, cmulc(c1, s));
    }
    build_rec<N, M + 1>(A, cf);
  }
}

template<int N, int K, class VT, class CF>
DEVINL void usweep_rec(VT& A, CF cf) {
  if constexpr (K < N) {
    C2 U00, U01, U10, U11;
    cf(K, U00, U01, U10, U11);
    g_u2<N, K>(A, U00, U01, U10, U11);
    usweep_rec<N, K + 1>(A, cf);
  }
}

template<int N, int K, class VT, class CF>
DEVINL void ry_rec(VT& A, CF cf) {
  if constexpr (K < N) {
    __half2 c2, s2, ns2;
    cf(K, c2, s2, ns2);
    g_ry<N, K>(A, c2, s2, ns2);
    ry_rec<N, K + 1>(A, cf);
  }
}

// ---------------- 4-qubit block I (verified math, SSA state) ----------------

template<int I>
DEVINL void sim4h(const float* __restrict__ xr, const float* __restrict__ w, float* z) {
  constexpr int PT[3][4]  = {{5, 4, 35, 34}, {3, 33, 31, 2}, {28, 32, 15, 16}};
  constexpr int ETA[3][4] = {{9, 8, 45, 44}, {7, 43, 41, 6}, {38, 42, 19, 20}};
  constexpr int PHI[3][4] = {{13, 12, 55, 54}, {11, 53, 51, 10}, {48, 52, 23, 24}};
  vreg16 A;
  vset(A, 0, mkamp(1.f, 0.f));
  build_rec<4, 0>(A, [&](int M, c32& u0, c32& u1) {
    float ce, se, cp, sp, cf, sf;
    load_sc(xr, ETA[I][M], PT[I][M], PHI[I][M], ce, se, cp, sp, cf, sf);
    mk_u01(ce, se, cp, sp, cf, sf, u0, u1);
  });
  chain_cnot<4, 0>(A);
  usweep_rec<4, 0>(A, [&](int K, C2& U00, C2& U01, C2& U10, C2& U11) {
    float ce, se, cp, sp, cf, sf;
    load_sc(xr, ETA[I][K], PT[I][K], PHI[I][K], ce, se, cp, sp, cf, sf);
    mk_U(ce, se, cp, sp, cf, sf, U00, U01, U10, U11);
  });

  // t->l CNOT block == flip q0,q1 (mask 12) iff parity(b2,b3) (i&3)
#pragma unroll
  for (int i = 0; i < 16; ++i)
    if (parc(i & 3) && !(i & 8)) {
      __half2 t = vget(A, i); vset(A, i, vget(A, i ^ 12)); vset(A, i ^ 12, t);
    }

  ry_rec<4, 0>(A, [&](int K, __half2& c2, __half2& s2, __half2& ns2) {
    float sv, cv; __sincosf(0.5f * w[K], &sv, &cv);
    c2 = __floats2half2_rn(cv, cv);
    s2 = __floats2half2_rn(sv, sv);
    ns2 = __floats2half2_rn(-sv, -sv);
  });

  // l->t CNOT block == flip q2,q3 (mask 3) iff parity(b0,b1) (i&12)
#pragma unroll
  for (int i = 0; i < 16; ++i)
    if (parc(i & 12) && !(i & 2)) {
      __half2 t = vget(A, i); vset(A, i, vget(A, i ^ 3)); vset(A, i ^ 3, t);
    }

  float cls[4];
#pragma unroll
  for (int c = 0; c < 4; ++c) cls[c] = 0.f;
#pragma unroll
  for (int i = 0; i < 16; ++i) cls[i & 3] = ampsq(vget(A, i), cls[i & 3]);
  float z0 = 0.f, z1 = 0.f;
#pragma unroll
  for (int c = 0; c < 4; ++c) {
    z0 += (c & 2) ? -cls[c] : cls[c];
    z1 += (c & 1) ? -cls[c] : cls[c];
  }
  z[0] = z0; z[1] = z1;
}

// ---------------- 7-qubit block (R12-verified math, S128 SSA state) ---------
// qubit k at bit 6-k. latent=(0..3) trash=(4,5,6) depth=4.

DEVINL void sim7(const float* __restrict__ xr, const float* __restrict__ wD,
                 float* z) {
  constexpr int PT[7]  = {0, 14, 30, 26, 29, 27, 17};
  constexpr int ETA[7] = {-1, 18, 40, 36, 39, 37, 21};  // -1 -> zeros (None)
  constexpr int PHI[7] = {1, 22, 50, 46, 49, 47, 25};

  S128 A;
  vset(A, 0, mkamp(1.f, 0.f));
  build_rec<7, 0>(A, [&](int M, c32& u0, c32& u1) {
    float ce, se, cp, sp, cf, sf;
    load_sc(xr, ETA[M], PT[M], PHI[M], ce, se, cp, sp, cf, sf);
    mk_u01(ce, se, cp, sp, cf, sf, u0, u1);
  });
  chain_cnot<7, 0>(A);
  usweep_rec<7, 0>(A, [&](int K, C2& U00, C2& U01, C2& U10, C2& U11) {
    float ce, se, cp, sp, cf, sf;
    load_sc(xr, ETA[K], PT[K], PHI[K], ce, se, cp, sp, cf, sf);
    mk_U(ce, se, cp, sp, cf, sf, U00, U01, U10, U11);
  });

  // depth loop kept rolled: body stays in L1I
#pragma unroll 1
  for (int d = 0; d < 4; ++d) {
    // t->l block == flip q0..q3 (mask 0x78) iff parity(q4,q5,q6) (i&7)
#pragma unroll
    for (int i = 0; i < 128; ++i)
      if (parc(i & 7) && !(i & 64)) {
        __half2 t = vget(A, i); vset(A, i, vget(A, i ^ 0x78)); vset(A, i ^ 0x78, t);
      }

    ry_rec<7, 0>(A, [&](int K, __half2& c2, __half2& s2, __half2& ns2) {
      float sv, cv; __sincosf(0.5f * wD[7 * d + K], &sv, &cv);
      c2 = __floats2half2_rn(cv, cv);
      s2 = __floats2half2_rn(sv, sv);
      ns2 = __floats2half2_rn(-sv, -sv);
    });

    // l->t block == flip q4..q6 (mask 7) iff parity(q0..q3) (i&0x78)
#pragma unroll
    for (int i = 0; i < 128; ++i)
      if (parc(i & 0x78) && !(i & 4)) {
        __half2 t = vget(A, i); vset(A, i, vget(A, i ^ 7)); vset(A, i ^ 7, t);
      }
  }

  float cls[8];
#pragma unroll
  for (int c = 0; c < 8; ++c) cls[c] = 0.f;
#pragma unroll
  for (int i = 0; i < 128; ++i) cls[i & 7] = ampsq(vget(A, i), cls[i & 7]);
  float z4 = 0.f, z5 = 0.f, z6 = 0.f;
#pragma unroll
  for (int c = 0; c < 8; ++c) {
    z4 += (c & 4) ? -cls[c] : cls[c];
    z5 += (c & 2) ? -cls[c] : cls[c];
    z6 += (c & 1) ? -cls[c] : cls[c];
  }
  z[0] = z4; z[1] = z5; z[2] = z6;
}

// ---------------- single fused-dispatch kernel, two block roles -------------

__global__ void __launch_bounds__(256, 2)
k_all(const float* __restrict__ x,
      const float* __restrict__ wA, const float* __restrict__ wB,
      const float* __restrict__ wC, const float* __restrict__ wD,
      float* __restrict__ out, int B, int gx) {
  const int bx = blockIdx.x;
  if (bx < gx) {
    // ABC role: one thread per element, all three 4q sims
    const int b = bx * 256 + threadIdx.x;
    if (b >= B) return;
    const float* xr = x + (size_t)b * 56;
    float o[6];
    sim4h<0>(xr, wA, &o[0]);
    sim4h<1>(xr, wB, &o[2]);
    sim4h<2>(xr, wC, &o[4]);
    float* op = out + (size_t)b * 9;
#pragma unroll
    for (int i = 0; i < 6; ++i) op[i] = o[i];
  } else {
    // 7q role: one thread per element, S128 state
    const int b = (bx - gx) * 256 + threadIdx.x;
    if (b >= B) return;
    const float* xr = x + (size_t)b * 56;
    float o[3];
    sim7(xr, wD, o);
    float* op = out + (size_t)b * 9 + 6;
    op[0] = o[0]; op[1] = o[1]; op[2] = o[2];
  }
}

// ---------------- launch ----------------------------------------------------

extern "C" void kernel_launch(void* const* d_in, const int* in_sizes, int n_in,
                              void* d_out, int out_size, void* d_ws, size_t ws_size,
                              hipStream_t stream) {
  const float* x  = (const float*)d_in[0];
  const float* wA = (const float*)d_in[1];
  const float* wB = (const float*)d_in[2];
  const float* wC = (const float*)d_in[3];
  const float* wD = (const float*)d_in[4];
  float* out = (float*)d_out;
  const int B = in_sizes[0] / 56;
  const int threads = 256;

  const int gx = (B + threads - 1) / threads;   // blocks per role
  k_all<<<2 * gx, threads, 0, stream>>>(x, wA, wB, wC, wD, out, B, gx);
}